// Round 2
// baseline (1048.207 us; speedup 1.0000x reference)
//
#include <hip/hip_runtime.h>

#define HC 128
#define FIN 128
#define NHEAD 4
#define NS_ATT 0.2f
#define NS_ACT 0.01f

__device__ __forceinline__ float lrelu(float v, float s) { return v >= 0.f ? v : s * v; }

// init: count=1 (self-loop), zero pooling buffers
__global__ void k_init(int* __restrict__ cnt, float* __restrict__ pool_sum,
                       int* __restrict__ pool_cnt, int N, int B) {
  int i = blockIdx.x * 256 + threadIdx.x;
  if (i < N) cnt[i] = 1;
  if (i < B * HC) pool_sum[i] = 0.f;
  if (i < B) pool_cnt[i] = 0;
}

// xh = x @ W  (+ fused a_src/a_dst head-dot epilogue)
// 256 threads: tx = output column (0..127), ty = row parity. 64 rows/block.
__global__ __launch_bounds__(256) void k_gemm(
    const float* __restrict__ x, const float* __restrict__ Wm,
    const float* __restrict__ att_s, const float* __restrict__ att_d,
    float* __restrict__ xh, float* __restrict__ a_src, float* __restrict__ a_dst,
    int N) {
  __shared__ __align__(16) float xs[8][FIN];
  const int tid = threadIdx.x, tx = tid & 127, ty = tid >> 7;
  const long base = (long)blockIdx.x * 64;
  float w[FIN];
#pragma unroll
  for (int k = 0; k < FIN; ++k) w[k] = Wm[k * HC + tx];
  const float asc = att_s[tx], adc = att_d[tx];
  for (int g = 0; g < 8; ++g) {
    const long r0 = base + g * 8;
#pragma unroll
    for (int q = 0; q < 4; ++q) {
      int idx = tid + q * 256;
      int lr = idx >> 7, col = idx & 127;
      long row = r0 + lr;
      xs[lr][col] = (row < N) ? x[row * FIN + col] : 0.f;
    }
    __syncthreads();
#pragma unroll
    for (int ii = 0; ii < 4; ++ii) {
      const int lr = 2 * ii + ty;
      const long row = r0 + lr;
      const float4* xr = (const float4*)xs[lr];
      float acc[4] = {0.f, 0.f, 0.f, 0.f};
#pragma unroll
      for (int k4 = 0; k4 < 32; ++k4) {
        float4 v = xr[k4];
        acc[k4 & 3] = fmaf(v.w, w[4 * k4 + 3],
                      fmaf(v.z, w[4 * k4 + 2],
                      fmaf(v.y, w[4 * k4 + 1],
                      fmaf(v.x, w[4 * k4 + 0], acc[k4 & 3]))));
      }
      float a = (acc[0] + acc[1]) + (acc[2] + acc[3]);
      if (row < N) {
        xh[row * HC + tx] = a;
        float ps = a * asc, pd = a * adc;
#pragma unroll
        for (int m = 16; m >= 1; m >>= 1) {
          ps += __shfl_xor(ps, m);
          pd += __shfl_xor(pd, m);
        }
        if ((tx & 31) == 0) {
          int h = tx >> 5;
          a_src[row * NHEAD + h] = ps;
          a_dst[row * NHEAD + h] = pd;
        }
      }
    }
    __syncthreads();
  }
}

__global__ void k_count(const int* __restrict__ ei, int* __restrict__ cnt, int E) {
  int i = blockIdx.x * 256 + threadIdx.x;
  if (i < E) atomicAdd(&cnt[ei[E + i]], 1);
}

__global__ void k_scanA(const int* __restrict__ cnt, int* __restrict__ offs,
                        int* __restrict__ part, int N) {
  __shared__ int s[256];
  int t = threadIdx.x, i = blockIdx.x * 256 + t;
  int v = (i < N) ? cnt[i] : 0;
  s[t] = v;
#pragma unroll
  for (int off = 1; off < 256; off <<= 1) {
    __syncthreads();
    int u = (t >= off) ? s[t - off] : 0;
    __syncthreads();
    s[t] += u;
  }
  if (i < N) offs[i] = s[t] - v;
  if (t == 255) part[blockIdx.x] = s[255];
}

__global__ void k_scanB(int* __restrict__ part, int NB) {
  __shared__ int s[1024];
  int t = threadIdx.x;
  int v = (t < NB) ? part[t] : 0;
  s[t] = v;
#pragma unroll
  for (int off = 1; off < 1024; off <<= 1) {
    __syncthreads();
    int u = (t >= off) ? s[t - off] : 0;
    __syncthreads();
    s[t] += u;
  }
  if (t < NB) part[t] = s[t] - v;
  if (t == 1023) part[NB] = s[1023];
}

__global__ void k_scanC(int* __restrict__ offs, const int* __restrict__ part, int N, int NB) {
  int i = blockIdx.x * 256 + threadIdx.x;
  if (i < N) offs[i] += part[i >> 8];
  else if (i == N) offs[N] = part[NB];
}

__global__ void k_selfloop(const int* __restrict__ offs, int* __restrict__ cursor,
                           int* __restrict__ csr_src, int N) {
  int i = blockIdx.x * 256 + threadIdx.x;
  if (i < N) {
    int o = offs[i];
    cursor[i] = o + 1;
    csr_src[o] = i;
  }
}

__global__ void k_fill(const int* __restrict__ ei, int* __restrict__ cursor,
                       int* __restrict__ csr_src, int E) {
  int i = blockIdx.x * 256 + threadIdx.x;
  if (i < E) {
    int s = ei[i], d = ei[E + i];
    int pos = atomicAdd(&cursor[d], 1);
    csr_src[pos] = s;
  }
}

// one wave per dst node: local softmax over CSR segment + weighted gather of xh[src]
__global__ __launch_bounds__(256) void k_agg(
    const int* __restrict__ csr_src, const int* __restrict__ offs,
    const float* __restrict__ a_src, const float* __restrict__ a_dst,
    const float* __restrict__ xh, const int* __restrict__ batch,
    const float* __restrict__ bias, float* __restrict__ pool_sum,
    int* __restrict__ pool_cnt, int N) {
  int wid = (blockIdx.x * 256 + threadIdx.x) >> 6;
  int lane = threadIdx.x & 63;
  if (wid >= N) return;
  const int n = wid;
  const int o0 = offs[n], deg = offs[n + 1] - o0;
  const float4 dv = ((const float4*)a_dst)[n];
  // pass A: per-head max
  float4 mx = make_float4(-1e30f, -1e30f, -1e30f, -1e30f);
  for (int i = lane; i < deg; i += 64) {
    int s = csr_src[o0 + i];
    float4 av = ((const float4*)a_src)[s];
    mx.x = fmaxf(mx.x, lrelu(av.x + dv.x, NS_ATT));
    mx.y = fmaxf(mx.y, lrelu(av.y + dv.y, NS_ATT));
    mx.z = fmaxf(mx.z, lrelu(av.z + dv.z, NS_ATT));
    mx.w = fmaxf(mx.w, lrelu(av.w + dv.w, NS_ATT));
  }
#pragma unroll
  for (int m = 32; m >= 1; m >>= 1) {
    mx.x = fmaxf(mx.x, __shfl_xor(mx.x, m));
    mx.y = fmaxf(mx.y, __shfl_xor(mx.y, m));
    mx.z = fmaxf(mx.z, __shfl_xor(mx.z, m));
    mx.w = fmaxf(mx.w, __shfl_xor(mx.w, m));
  }
  // pass B: per-head sum of exp
  float4 sm = make_float4(0.f, 0.f, 0.f, 0.f);
  for (int i = lane; i < deg; i += 64) {
    int s = csr_src[o0 + i];
    float4 av = ((const float4*)a_src)[s];
    sm.x += __expf(lrelu(av.x + dv.x, NS_ATT) - mx.x);
    sm.y += __expf(lrelu(av.y + dv.y, NS_ATT) - mx.y);
    sm.z += __expf(lrelu(av.z + dv.z, NS_ATT) - mx.z);
    sm.w += __expf(lrelu(av.w + dv.w, NS_ATT) - mx.w);
  }
#pragma unroll
  for (int m = 32; m >= 1; m >>= 1) {
    sm.x += __shfl_xor(sm.x, m);
    sm.y += __shfl_xor(sm.y, m);
    sm.z += __shfl_xor(sm.z, m);
    sm.w += __shfl_xor(sm.w, m);
  }
  const int h = lane >> 4;  // head of channels 2*lane, 2*lane+1
  const float mh = (h == 0) ? mx.x : (h == 1) ? mx.y : (h == 2) ? mx.z : mx.w;
  const float sh = (h == 0) ? sm.x : (h == 1) ? sm.y : (h == 2) ? sm.z : sm.w;
  const float dh = (h == 0) ? dv.x : (h == 1) ? dv.y : (h == 2) ? dv.z : dv.w;
  const float inv = 1.f / (sh + 1e-16f);
  // pass C: weighted accumulate of xh[src], 2 channels per lane
  float2 acc = make_float2(0.f, 0.f);
  const float2* xh2 = (const float2*)xh;
  for (int j = 0; j < deg; ++j) {
    int s = csr_src[o0 + j];                 // wave-uniform broadcast
    float ah = a_src[s * NHEAD + h];         // 4 addrs per wave, L2-resident
    float wgt = __expf(lrelu(ah + dh, NS_ATT) - mh);
    float2 v = xh2[(long)s * 64 + lane];     // 512B coalesced
    acc.x = fmaf(wgt, v.x, acc.x);
    acc.y = fmaf(wgt, v.y, acc.y);
  }
  const float2 bv = ((const float2*)bias)[lane];
  float rx = lrelu(acc.x * inv + bv.x, NS_ACT);
  float ry = lrelu(acc.y * inv + bv.y, NS_ACT);
  int b = batch[n];
  atomicAdd(&pool_sum[b * HC + 2 * lane], rx);
  atomicAdd(&pool_sum[b * HC + 2 * lane + 1], ry);
  if (lane == 0) atomicAdd(&pool_cnt[b], 1);
}

__global__ void k_final(const float* __restrict__ pool_sum, const int* __restrict__ pool_cnt,
                        const float* __restrict__ lin_w, const float* __restrict__ lin_b,
                        float* __restrict__ out, int B) {
  int b = blockIdx.x;
  __shared__ float pl[HC];
  int t = threadIdx.x;
  float c = fmaxf((float)pool_cnt[b], 1.0f);
  pl[t] = pool_sum[b * HC + t] / c;
  __syncthreads();
  if (t < 10) {
    float a = lin_b[t];
    for (int k = 0; k < HC; ++k) a = fmaf(pl[k], lin_w[t * HC + k], a);
    out[b * 10 + t] = a;
  }
}

extern "C" void kernel_launch(void* const* d_in, const int* in_sizes, int n_in,
                              void* d_out, int out_size, void* d_ws, size_t ws_size,
                              hipStream_t stream) {
  const float* x = (const float*)d_in[0];
  const int* ei = (const int*)d_in[1];      // int64 in reference -> int32 on device
  const int* batch = (const int*)d_in[2];   // int64 in reference -> int32 on device
  const float* Wm = (const float*)d_in[4];
  const float* att_s = (const float*)d_in[5];
  const float* att_d = (const float*)d_in[6];
  const float* bias = (const float*)d_in[7];
  const float* lin_w = (const float*)d_in[8];
  const float* lin_b = (const float*)d_in[9];
  float* out = (float*)d_out;

  const int N = in_sizes[2];
  const int E = in_sizes[1] / 2;
  const int B = out_size / 10;
  const int NB = (N + 255) / 256;  // must be <= 1024 (N <= 262144)

  char* p = (char*)d_ws;
  auto carve = [&](size_t bytes) {
    void* r = (void*)p;
    p += (bytes + 255) & ~(size_t)255;
    return r;
  };
  float* xh = (float*)carve((size_t)N * HC * 4);
  float* a_src = (float*)carve((size_t)N * NHEAD * 4);
  float* a_dst = (float*)carve((size_t)N * NHEAD * 4);
  int* cnt = (int*)carve((size_t)N * 4);
  int* offs = (int*)carve((size_t)(N + 1) * 4);
  int* cursor = (int*)carve((size_t)N * 4);
  int* part = (int*)carve((size_t)(NB + 2) * 4);
  int* csr_src = (int*)carve((size_t)(N + (size_t)E) * 4);
  float* pool_sum = (float*)carve((size_t)B * HC * 4);
  int* pool_cnt = (int*)carve((size_t)B * 4);

  const int initN = (N > B * HC) ? N : B * HC;
  k_init<<<(initN + 255) / 256, 256, 0, stream>>>(cnt, pool_sum, pool_cnt, N, B);
  k_gemm<<<(N + 63) / 64, 256, 0, stream>>>(x, Wm, att_s, att_d, xh, a_src, a_dst, N);
  k_count<<<(E + 255) / 256, 256, 0, stream>>>(ei, cnt, E);
  k_scanA<<<NB, 256, 0, stream>>>(cnt, offs, part, N);
  k_scanB<<<1, 1024, 0, stream>>>(part, NB);
  k_scanC<<<(N + 256) / 256, 256, 0, stream>>>(offs, part, N, NB);
  k_selfloop<<<(N + 255) / 256, 256, 0, stream>>>(offs, cursor, csr_src, N);
  k_fill<<<(E + 255) / 256, 256, 0, stream>>>(ei, cursor, csr_src, E);
  k_agg<<<(N + 3) / 4, 256, 0, stream>>>(csr_src, offs, a_src, a_dst, xh, batch, bias,
                                         pool_sum, pool_cnt, N);
  k_final<<<B, 128, 0, stream>>>(pool_sum, pool_cnt, lin_w, lin_b, out, B);
}

// Round 3
// 916.849 us; speedup vs baseline: 1.1433x; 1.1433x over previous
//
#include <hip/hip_runtime.h>

#define HC 128
#define FIN 128
#define NHEAD 4
#define NS_ATT 0.2f
#define NS_ACT 0.01f

__device__ __forceinline__ float lrelu(float v, float s) { return v >= 0.f ? v : s * v; }

// init: count=1 (self-loop), zero pooling buffers
__global__ void k_init(int* __restrict__ cnt, float* __restrict__ pool_sum,
                       int* __restrict__ pool_cnt, int N, int B) {
  int i = blockIdx.x * 256 + threadIdx.x;
  if (i < N) cnt[i] = 1;
  if (i < B * HC) pool_sum[i] = 0.f;
  if (i < B) pool_cnt[i] = 0;
}

// xh = x @ W  (+ fused a_src/a_dst head-dot epilogue)
__global__ __launch_bounds__(256) void k_gemm(
    const float* __restrict__ x, const float* __restrict__ Wm,
    const float* __restrict__ att_s, const float* __restrict__ att_d,
    float* __restrict__ xh, float* __restrict__ a_src, float* __restrict__ a_dst,
    int N) {
  __shared__ __align__(16) float xs[8][FIN];
  const int tid = threadIdx.x, tx = tid & 127, ty = tid >> 7;
  const long base = (long)blockIdx.x * 64;
  float w[FIN];
#pragma unroll
  for (int k = 0; k < FIN; ++k) w[k] = Wm[k * HC + tx];
  const float asc = att_s[tx], adc = att_d[tx];
  for (int g = 0; g < 8; ++g) {
    const long r0 = base + g * 8;
#pragma unroll
    for (int q = 0; q < 4; ++q) {
      int idx = tid + q * 256;
      int lr = idx >> 7, col = idx & 127;
      long row = r0 + lr;
      xs[lr][col] = (row < N) ? x[row * FIN + col] : 0.f;
    }
    __syncthreads();
#pragma unroll
    for (int ii = 0; ii < 4; ++ii) {
      const int lr = 2 * ii + ty;
      const long row = r0 + lr;
      const float4* xr = (const float4*)xs[lr];
      float acc[4] = {0.f, 0.f, 0.f, 0.f};
#pragma unroll
      for (int k4 = 0; k4 < 32; ++k4) {
        float4 v = xr[k4];
        acc[k4 & 3] = fmaf(v.w, w[4 * k4 + 3],
                      fmaf(v.z, w[4 * k4 + 2],
                      fmaf(v.y, w[4 * k4 + 1],
                      fmaf(v.x, w[4 * k4 + 0], acc[k4 & 3]))));
      }
      float a = (acc[0] + acc[1]) + (acc[2] + acc[3]);
      if (row < N) {
        xh[row * HC + tx] = a;
        float ps = a * asc, pd = a * adc;
#pragma unroll
        for (int m = 16; m >= 1; m >>= 1) {
          ps += __shfl_xor(ps, m);
          pd += __shfl_xor(pd, m);
        }
        if ((tx & 31) == 0) {
          int h = tx >> 5;
          a_src[row * NHEAD + h] = ps;
          a_dst[row * NHEAD + h] = pd;
        }
      }
    }
    __syncthreads();
  }
}

__global__ void k_count(const int* __restrict__ ei, int* __restrict__ cnt, int E) {
  int i = blockIdx.x * 256 + threadIdx.x;
  if (i < E) atomicAdd(&cnt[ei[E + i]], 1);
}

__global__ void k_scanA(const int* __restrict__ cnt, int* __restrict__ offs,
                        int* __restrict__ part, int N) {
  __shared__ int s[256];
  int t = threadIdx.x, i = blockIdx.x * 256 + t;
  int v = (i < N) ? cnt[i] : 0;
  s[t] = v;
#pragma unroll
  for (int off = 1; off < 256; off <<= 1) {
    __syncthreads();
    int u = (t >= off) ? s[t - off] : 0;
    __syncthreads();
    s[t] += u;
  }
  if (i < N) offs[i] = s[t] - v;
  if (t == 255) part[blockIdx.x] = s[255];
}

__global__ void k_scanB(int* __restrict__ part, int NB) {
  __shared__ int s[1024];
  int t = threadIdx.x;
  int v = (t < NB) ? part[t] : 0;
  s[t] = v;
#pragma unroll
  for (int off = 1; off < 1024; off <<= 1) {
    __syncthreads();
    int u = (t >= off) ? s[t - off] : 0;
    __syncthreads();
    s[t] += u;
  }
  if (t < NB) part[t] = s[t] - v;
  if (t == 1023) part[NB] = s[1023];
}

__global__ void k_scanC(int* __restrict__ offs, const int* __restrict__ part, int N, int NB) {
  int i = blockIdx.x * 256 + threadIdx.x;
  if (i < N) offs[i] += part[i >> 8];
  else if (i == N) offs[N] = part[NB];
}

__global__ void k_selfloop(const int* __restrict__ offs, int* __restrict__ cursor,
                           int* __restrict__ csr_src, int N) {
  int i = blockIdx.x * 256 + threadIdx.x;
  if (i < N) {
    int o = offs[i];
    cursor[i] = o + 1;
    csr_src[o] = i;
  }
}

__global__ void k_fill(const int* __restrict__ ei, int* __restrict__ cursor,
                       int* __restrict__ csr_src, int E) {
  int i = blockIdx.x * 256 + threadIdx.x;
  if (i < E) {
    int s = ei[i], d = ei[E + i];
    int pos = atomicAdd(&cursor[d], 1);
    csr_src[pos] = s;
  }
}

// one wave per dst node. Single fused pass (no max subtraction: |e|<~10, exp safe in fp32).
// Per 64-edge chunk: lane-parallel index + a_src gather + weight compute; then 16-lane/edge
// gather-accumulate with 4 edges concurrent (groups) x2 unroll for MLP.
__global__ __launch_bounds__(256) void k_agg(
    const int* __restrict__ csr_src, const int* __restrict__ offs,
    const float* __restrict__ a_src, const float* __restrict__ a_dst,
    const float* __restrict__ xh, const int* __restrict__ batch,
    const float* __restrict__ bias, float* __restrict__ pool_sum,
    int* __restrict__ pool_cnt, int N) {
  const int wid = (blockIdx.x * 256 + threadIdx.x) >> 6;
  const int lane = threadIdx.x & 63;
  if (wid >= N) return;
  const int n = wid;
  const int o0 = offs[n], deg = offs[n + 1] - o0;
  const float4 dv = ((const float4*)a_dst)[n];
  const int l16 = lane & 15, g = lane >> 4, h = l16 >> 2;
  const float4* __restrict__ xh4 = (const float4*)xh;

  float4 sm = make_float4(0.f, 0.f, 0.f, 0.f);
  float4 ac0 = make_float4(0.f, 0.f, 0.f, 0.f);
  float4 ac1 = make_float4(0.f, 0.f, 0.f, 0.f);

  for (int c0 = 0; c0 < deg; c0 += 64) {
    const int cl = min(64, deg - c0);
    int sj = 0;
    float4 w4 = make_float4(0.f, 0.f, 0.f, 0.f);
    if (lane < cl) {
      sj = csr_src[o0 + c0 + lane];
      float4 av = ((const float4*)a_src)[sj];
      w4.x = __expf(lrelu(av.x + dv.x, NS_ATT));
      w4.y = __expf(lrelu(av.y + dv.y, NS_ATT));
      w4.z = __expf(lrelu(av.z + dv.z, NS_ATT));
      w4.w = __expf(lrelu(av.w + dv.w, NS_ATT));
      sm.x += w4.x; sm.y += w4.y; sm.z += w4.z; sm.w += w4.w;
    }
    for (int j = 0; j < cl; j += 8) {
      const int e0 = j + g, e1 = j + g + 4;
      const int s0 = __shfl(sj, e0), s1 = __shfl(sj, e1);
      const float w0x = __shfl(w4.x, e0), w0y = __shfl(w4.y, e0);
      const float w0z = __shfl(w4.z, e0), w0w = __shfl(w4.w, e0);
      const float w1x = __shfl(w4.x, e1), w1y = __shfl(w4.y, e1);
      const float w1z = __shfl(w4.z, e1), w1w = __shfl(w4.w, e1);
      const float w0 = (h == 0) ? w0x : (h == 1) ? w0y : (h == 2) ? w0z : w0w;
      const float w1 = (h == 0) ? w1x : (h == 1) ? w1y : (h == 2) ? w1z : w1w;
      if (e0 < cl) {
        const float4 v0 = xh4[(long)s0 * 32 + l16 * 2];
        const float4 v1 = xh4[(long)s0 * 32 + l16 * 2 + 1];
        ac0.x = fmaf(w0, v0.x, ac0.x); ac0.y = fmaf(w0, v0.y, ac0.y);
        ac0.z = fmaf(w0, v0.z, ac0.z); ac0.w = fmaf(w0, v0.w, ac0.w);
        ac1.x = fmaf(w0, v1.x, ac1.x); ac1.y = fmaf(w0, v1.y, ac1.y);
        ac1.z = fmaf(w0, v1.z, ac1.z); ac1.w = fmaf(w0, v1.w, ac1.w);
      }
      if (e1 < cl) {
        const float4 v0 = xh4[(long)s1 * 32 + l16 * 2];
        const float4 v1 = xh4[(long)s1 * 32 + l16 * 2 + 1];
        ac0.x = fmaf(w1, v0.x, ac0.x); ac0.y = fmaf(w1, v0.y, ac0.y);
        ac0.z = fmaf(w1, v0.z, ac0.z); ac0.w = fmaf(w1, v0.w, ac0.w);
        ac1.x = fmaf(w1, v1.x, ac1.x); ac1.y = fmaf(w1, v1.y, ac1.y);
        ac1.z = fmaf(w1, v1.z, ac1.z); ac1.w = fmaf(w1, v1.w, ac1.w);
      }
    }
  }

  // reduce denominator across all 64 lanes
#pragma unroll
  for (int m = 32; m >= 1; m >>= 1) {
    sm.x += __shfl_xor(sm.x, m);
    sm.y += __shfl_xor(sm.y, m);
    sm.z += __shfl_xor(sm.z, m);
    sm.w += __shfl_xor(sm.w, m);
  }
  // reduce accumulators across the 4 groups (bits 4,5)
#pragma unroll
  for (int m = 32; m >= 16; m >>= 1) {
    ac0.x += __shfl_xor(ac0.x, m); ac0.y += __shfl_xor(ac0.y, m);
    ac0.z += __shfl_xor(ac0.z, m); ac0.w += __shfl_xor(ac0.w, m);
    ac1.x += __shfl_xor(ac1.x, m); ac1.y += __shfl_xor(ac1.y, m);
    ac1.z += __shfl_xor(ac1.z, m); ac1.w += __shfl_xor(ac1.w, m);
  }

  const float sh = (h == 0) ? sm.x : (h == 1) ? sm.y : (h == 2) ? sm.z : sm.w;
  const float inv = 1.f / (sh + 1e-16f);
  // lane writes channels l16*8 + g*2, +1
  float r0, r1;
  if (g == 0)      { r0 = ac0.x; r1 = ac0.y; }
  else if (g == 1) { r0 = ac0.z; r1 = ac0.w; }
  else if (g == 2) { r0 = ac1.x; r1 = ac1.y; }
  else             { r0 = ac1.z; r1 = ac1.w; }
  const int ch = l16 * 8 + g * 2;
  r0 = lrelu(r0 * inv + bias[ch], NS_ACT);
  r1 = lrelu(r1 * inv + bias[ch + 1], NS_ACT);
  const int b = batch[n];
  atomicAdd(&pool_sum[b * HC + ch], r0);
  atomicAdd(&pool_sum[b * HC + ch + 1], r1);
  if (lane == 0) atomicAdd(&pool_cnt[b], 1);
}

__global__ void k_final(const float* __restrict__ pool_sum, const int* __restrict__ pool_cnt,
                        const float* __restrict__ lin_w, const float* __restrict__ lin_b,
                        float* __restrict__ out, int B) {
  int b = blockIdx.x;
  __shared__ float pl[HC];
  int t = threadIdx.x;
  float c = fmaxf((float)pool_cnt[b], 1.0f);
  pl[t] = pool_sum[b * HC + t] / c;
  __syncthreads();
  if (t < 10) {
    float a = lin_b[t];
    for (int k = 0; k < HC; ++k) a = fmaf(pl[k], lin_w[t * HC + k], a);
    out[b * 10 + t] = a;
  }
}

extern "C" void kernel_launch(void* const* d_in, const int* in_sizes, int n_in,
                              void* d_out, int out_size, void* d_ws, size_t ws_size,
                              hipStream_t stream) {
  const float* x = (const float*)d_in[0];
  const int* ei = (const int*)d_in[1];      // int64 in reference -> int32 on device
  const int* batch = (const int*)d_in[2];   // int64 in reference -> int32 on device
  const float* Wm = (const float*)d_in[4];
  const float* att_s = (const float*)d_in[5];
  const float* att_d = (const float*)d_in[6];
  const float* bias = (const float*)d_in[7];
  const float* lin_w = (const float*)d_in[8];
  const float* lin_b = (const float*)d_in[9];
  float* out = (float*)d_out;

  const int N = in_sizes[2];
  const int E = in_sizes[1] / 2;
  const int B = out_size / 10;
  const int NB = (N + 255) / 256;  // must be <= 1024 (N <= 262144)

  char* p = (char*)d_ws;
  auto carve = [&](size_t bytes) {
    void* r = (void*)p;
    p += (bytes + 255) & ~(size_t)255;
    return r;
  };
  float* xh = (float*)carve((size_t)N * HC * 4);
  float* a_src = (float*)carve((size_t)N * NHEAD * 4);
  float* a_dst = (float*)carve((size_t)N * NHEAD * 4);
  int* cnt = (int*)carve((size_t)N * 4);
  int* offs = (int*)carve((size_t)(N + 1) * 4);
  int* cursor = (int*)carve((size_t)N * 4);
  int* part = (int*)carve((size_t)(NB + 2) * 4);
  int* csr_src = (int*)carve((size_t)(N + (size_t)E) * 4);
  float* pool_sum = (float*)carve((size_t)B * HC * 4);
  int* pool_cnt = (int*)carve((size_t)B * 4);

  const int initN = (N > B * HC) ? N : B * HC;
  k_init<<<(initN + 255) / 256, 256, 0, stream>>>(cnt, pool_sum, pool_cnt, N, B);
  k_gemm<<<(N + 63) / 64, 256, 0, stream>>>(x, Wm, att_s, att_d, xh, a_src, a_dst, N);
  k_count<<<(E + 255) / 256, 256, 0, stream>>>(ei, cnt, E);
  k_scanA<<<NB, 256, 0, stream>>>(cnt, offs, part, N);
  k_scanB<<<1, 1024, 0, stream>>>(part, NB);
  k_scanC<<<(N + 256) / 256, 256, 0, stream>>>(offs, part, N, NB);
  k_selfloop<<<(N + 255) / 256, 256, 0, stream>>>(offs, cursor, csr_src, N);
  k_fill<<<(E + 255) / 256, 256, 0, stream>>>(ei, cursor, csr_src, E);
  k_agg<<<(N + 3) / 4, 256, 0, stream>>>(csr_src, offs, a_src, a_dst, xh, batch, bias,
                                         pool_sum, pool_cnt, N);
  k_final<<<B, 128, 0, stream>>>(pool_sum, pool_cnt, lin_w, lin_b, out, B);
}